// Round 4
// baseline (813.359 us; speedup 1.0000x reference)
//
#include <hip/hip_runtime.h>
#include <hip/hip_bf16.h>
#include <cstddef>

typedef short bf16x8 __attribute__((ext_vector_type(8)));
typedef float f32x4 __attribute__((ext_vector_type(4)));

__device__ __forceinline__ unsigned short f2bf(float x) {
  __hip_bfloat16 h = __float2bfloat16(x);
  unsigned short u; __builtin_memcpy(&u, &h, 2); return u;
}
// pack two f32 -> 2x bf16 (lo,hi), round-half-up (cheap, bias < 2^-9 rel)
__device__ __forceinline__ unsigned int pack_bf(float lo, float hi) {
  unsigned int a, b;
  __builtin_memcpy(&a, &lo, 4); __builtin_memcpy(&b, &hi, 4);
  a += 0x8000u; b += 0x8000u;
  return (b & 0xFFFF0000u) | (a >> 16);
}

// ---------------- weight fp32 -> bf16 convert ----------------
__global__ __launch_bounds__(256) void f2bf_kernel(
    const float* __restrict__ src, unsigned short* __restrict__ dst, int n4)
{
  int i = blockIdx.x * 256 + threadIdx.x;
  if (i < n4) {
    float4 v = *(const float4*)(src + (size_t)i * 4);
    ushort4 o;
    o.x = f2bf(v.x); o.y = f2bf(v.y); o.z = f2bf(v.z); o.w = f2bf(v.w);
    *(ushort4*)(dst + (size_t)i * 4) = o;
  }
}

// ---------------- conv1d (circular, k=3) + positional embedding ----------------
__global__ __launch_bounds__(256) void conv_pe_kernel(
    const float* __restrict__ x, const float* __restrict__ cw,
    const float* __restrict__ cb,
    float* __restrict__ outf, unsigned short* __restrict__ outb)
{
  const int L = 2048, CIN = 32;
  int b  = blockIdx.x >> 8;
  int l0 = (blockIdx.x & 255) << 3;
  int t  = threadIdx.x;
  __shared__ float xs[10][32];
  for (int idx = t; idx < 320; idx += 256) {
    int rr = idx >> 5, ci = idx & 31;
    int gl = (l0 - 1 + rr + L) & (L - 1);
    xs[rr][ci] = x[((size_t)b * L + gl) * CIN + ci];
  }
  __syncthreads();
  int e0 = t << 1;
  float acc0[8], acc1[8];
  float bb0 = cb[e0], bb1 = cb[e0 + 1];
#pragma unroll
  for (int li = 0; li < 8; li++) { acc0[li] = bb0; acc1[li] = bb1; }
  const float* w0p = cw + (size_t)e0 * 96;
  const float* w1p = w0p + 96;
  for (int ci = 0; ci < 32; ci++) {
#pragma unroll
    for (int kk = 0; kk < 3; kk++) {
      float w0 = w0p[ci * 3 + kk];
      float w1 = w1p[ci * 3 + kk];
#pragma unroll
      for (int li = 0; li < 8; li++) {
        float xv = xs[li + kk][ci];
        acc0[li] += xv * w0;
        acc1[li] += xv * w1;
      }
    }
  }
  float dv = __expf((float)e0 * (-9.210340371976184f / 512.0f));
#pragma unroll
  for (int li = 0; li < 8; li++) {
    int l = l0 + li;
    float arg = (float)l * dv;
    float sv = sinf(arg), cv = cosf(arg);
    float2 o; o.x = acc0[li] + sv; o.y = acc1[li] + cv;
    size_t off = ((size_t)b * L + l) * 512 + e0;
    *(float2*)&outf[off] = o;
    ushort2 ob; ob.x = f2bf(o.x); ob.y = f2bf(o.y);
    *(ushort2*)&outb[off] = ob;
  }
}

// ---------------- bf16 MFMA GEMM: Y[M,N] = X[M,512] @ W[N,512]^T + bias ----------
// EPI 0: Y bf16.  EPI 1: Y f32 = acc + bias + R(f32).  EPI 2: SiLU -> Y bf16.
// QSCALE: multiply cols [0,512) by softmax prescale (for fused Q scaling).
template<int EPI, int QSCALE>
__global__ __launch_bounds__(256) void gemm_bf(
    const unsigned short* __restrict__ X,
    const unsigned short* __restrict__ W,
    const float* __restrict__ bias,
    const float* __restrict__ R,
    unsigned short* __restrict__ Yb,
    float* __restrict__ Yf,
    int N)
{
  const int K = 512;
  __shared__ unsigned short Xs[128 * 64];
  __shared__ unsigned short Ws[128 * 64];
  int t = threadIdx.x;
  int lane = t & 63, wv = t >> 6;
  int g = lane >> 4, li = lane & 15;
  int m0 = (blockIdx.x & 63) << 7;
  int n0 = (blockIdx.x >> 6) << 7;
  int wm = (wv >> 1) << 6, wn = (wv & 1) << 6;

  int srow = t >> 1, shalf = t & 1;
  const unsigned short* Xg = X + (size_t)(m0 + srow) * K + shalf * 32;
  const unsigned short* Wg = W + (size_t)(n0 + srow) * K + shalf * 32;
  int sw = srow & 7;

  f32x4 acc[4][4];
#pragma unroll
  for (int a = 0; a < 4; a++)
#pragma unroll
    for (int b2 = 0; b2 < 4; b2++) acc[a][b2] = (f32x4){0.f, 0.f, 0.f, 0.f};

  for (int k0 = 0; k0 < K; k0 += 64) {
    bf16x8 xr[4], wr[4];
#pragma unroll
    for (int j = 0; j < 4; j++) {
      xr[j] = *(const bf16x8*)(Xg + k0 + j * 8);
      wr[j] = *(const bf16x8*)(Wg + k0 + j * 8);
    }
    __syncthreads();
#pragma unroll
    for (int j = 0; j < 4; j++) {
      ((bf16x8*)Xs)[srow * 8 + ((shalf * 4 + j) ^ sw)] = xr[j];
      ((bf16x8*)Ws)[srow * 8 + ((shalf * 4 + j) ^ sw)] = wr[j];
    }
    __syncthreads();
#pragma unroll
    for (int s = 0; s < 2; s++) {
      bf16x8 af[4], bfr[4];
#pragma unroll
      for (int mt = 0; mt < 4; mt++) {
        int row = wm + 16 * mt + li;
        af[mt] = ((const bf16x8*)Xs)[row * 8 + ((g + 4 * s) ^ (row & 7))];
      }
#pragma unroll
      for (int nt = 0; nt < 4; nt++) {
        int row = wn + 16 * nt + li;
        bfr[nt] = ((const bf16x8*)Ws)[row * 8 + ((g + 4 * s) ^ (row & 7))];
      }
#pragma unroll
      for (int mt = 0; mt < 4; mt++)
#pragma unroll
        for (int nt = 0; nt < 4; nt++)
          acc[mt][nt] = __builtin_amdgcn_mfma_f32_16x16x32_bf16(
              af[mt], bfr[nt], acc[mt][nt], 0, 0, 0);
    }
  }
  float bv[4];
#pragma unroll
  for (int nt = 0; nt < 4; nt++) bv[nt] = bias[n0 + wn + 16 * nt + li];
#pragma unroll
  for (int mt = 0; mt < 4; mt++) {
#pragma unroll
    for (int i = 0; i < 4; i++) {
      size_t roff = (size_t)(m0 + wm + 16 * mt + 4 * g + i) * N;
#pragma unroll
      for (int nt = 0; nt < 4; nt++) {
        int col = n0 + wn + 16 * nt + li;
        float v = acc[mt][nt][i] + bv[nt];
        if (EPI == 1) {
          v += R[roff + col];
          Yf[roff + col] = v;
        } else if (EPI == 2) {
          v = v / (1.f + __expf(-v));
          Yb[roff + col] = f2bf(v);
        } else {
          if (QSCALE && col < 512) v *= 0.18033688011112042f;  // 0.125*log2(e)
          Yb[roff + col] = f2bf(v);
        }
      }
    }
  }
}

// ---------------- V transpose: qkv_bf V-part -> Vt[32][64][2048] ----------------
__global__ __launch_bounds__(256) void vtrans_kernel(
    const unsigned short* __restrict__ qkv, unsigned short* __restrict__ Vt)
{
  int ki = blockIdx.x & 31, bh = blockIdx.x >> 5;
  int b = bh >> 3, h = bh & 7;
  int kt = ki << 6;
  __shared__ unsigned short T[64][72];
  int t = threadIdx.x;
  int r = t >> 2, c0 = (t & 3) << 4;
  const unsigned short* src =
      qkv + ((size_t)(b * 2048 + kt + r)) * 1536 + 1024 + h * 64 + c0;
  bf16x8 a0 = *(const bf16x8*)src;
  bf16x8 a1 = *(const bf16x8*)(src + 8);
  *(bf16x8*)&T[r][c0] = a0;
  *(bf16x8*)&T[r][c0 + 8] = a1;
  __syncthreads();
  int d = t >> 2, k0 = (t & 3) << 4;
  bf16x8 v0, v1;
#pragma unroll
  for (int j = 0; j < 8; j++) v0[j] = (short)T[k0 + j][d];
#pragma unroll
  for (int j = 0; j < 8; j++) v1[j] = (short)T[k0 + 8 + j][d];
  unsigned short* dst = Vt + ((size_t)bh * 64 + d) * 2048 + kt + k0;
  *(bf16x8*)dst = v0;
  *(bf16x8*)(dst + 8) = v1;
}

// ---------------- MFMA flash attention: H=8, HD=64, L=2048 ----------------
// grid: 32 q-tiles x 32 bh; 256 thr = 4 waves, 16 q-rows/wave, 64-key tiles
// Q comes PRE-SCALED by 0.125*log2(e): softmax uses exp2 directly.
__global__ __launch_bounds__(256) void attn_mfma(
    const unsigned short* __restrict__ qkv,  // [8192,1536] bf16 (Q prescaled)
    const unsigned short* __restrict__ Vt,   // [32,64,2048] bf16
    unsigned short* __restrict__ ctx)        // [8192,512] bf16
{
  const int L = 2048;
  int qi = blockIdx.x & 31, bh = blockIdx.x >> 5;
  int b = bh >> 3, h = bh & 7;
  int q0 = qi << 6;
  size_t tb = (size_t)b * L;
  int t = threadIdx.x, lane = t & 63, wv = t >> 6;
  int g = lane >> 4, li = lane & 15;

  __shared__ unsigned short Ks[64 * 64];   // [key][d], slot^=(key&7)
  __shared__ unsigned short Vs[64 * 64];   // [d][key], slot^=(d&7)
  __shared__ unsigned short Ps[4][16 * 64];// per-wave [q][key], slot^=(q&7)

  bf16x8 qf[2];
  {
    const unsigned short* qp =
        qkv + (tb + q0 + wv * 16 + li) * 1536 + h * 64 + g * 8;
    qf[0] = *(const bf16x8*)qp;
    qf[1] = *(const bf16x8*)(qp + 32);
  }

  f32x4 acc_o[4];
#pragma unroll
  for (int nt = 0; nt < 4; nt++) acc_o[nt] = (f32x4){0.f, 0.f, 0.f, 0.f};
  float m_run = -1e30f, l_run = 0.f;

  int sr = t >> 2, sc = t & 3;
  const unsigned short* Kg = qkv + (tb + sr) * 1536 + 512 + h * 64 + sc * 16;
  const unsigned short* Vg = Vt + ((size_t)bh * 64 + sr) * 2048 + sc * 16;
  int ssw = sr & 7;

  for (int kt = 0; kt < L; kt += 64) {
    bf16x8 kr0 = *(const bf16x8*)(Kg + (size_t)kt * 1536);
    bf16x8 kr1 = *(const bf16x8*)(Kg + (size_t)kt * 1536 + 8);
    bf16x8 vr0 = *(const bf16x8*)(Vg + kt);
    bf16x8 vr1 = *(const bf16x8*)(Vg + kt + 8);
    __syncthreads();
    ((bf16x8*)Ks)[sr * 8 + ((sc * 2) ^ ssw)]     = kr0;
    ((bf16x8*)Ks)[sr * 8 + ((sc * 2 + 1) ^ ssw)] = kr1;
    ((bf16x8*)Vs)[sr * 8 + ((sc * 2) ^ ssw)]     = vr0;
    ((bf16x8*)Vs)[sr * 8 + ((sc * 2 + 1) ^ ssw)] = vr1;
    __syncthreads();

    // S^T[key][q] = K . Q^T  (A = K rows, B = Q);  scores already exp2-scaled
    f32x4 s_[4];
#pragma unroll
    for (int mt = 0; mt < 4; mt++) s_[mt] = (f32x4){0.f, 0.f, 0.f, 0.f};
#pragma unroll
    for (int s = 0; s < 2; s++) {
#pragma unroll
      for (int mt = 0; mt < 4; mt++) {
        int row = 16 * mt + li;
        bf16x8 kf = ((const bf16x8*)Ks)[row * 8 + ((g + 4 * s) ^ (row & 7))];
        s_[mt] = __builtin_amdgcn_mfma_f32_16x16x32_bf16(kf, qf[s], s_[mt], 0, 0, 0);
      }
    }

    // tile max for this lane's q-row (lane owns q=li; scores at keys 16mt+4g+i)
    float mx = fmaxf(fmaxf(s_[0][0], s_[0][1]), fmaxf(s_[0][2], s_[0][3]));
#pragma unroll
    for (int mt = 1; mt < 4; mt++)
      mx = fmaxf(mx, fmaxf(fmaxf(s_[mt][0], s_[mt][1]), fmaxf(s_[mt][2], s_[mt][3])));
    mx = fmaxf(mx, __shfl_xor(mx, 16));
    mx = fmaxf(mx, __shfl_xor(mx, 32));

    // defer-max (T13): rescale only when some row's max grew past THR=8
    if (__any(mx > m_run + 8.0f)) {
      float m_new = fmaxf(m_run, mx);
      float corr = exp2f(m_run - m_new);
      float c0 = __shfl(corr, 4 * g + 0);
      float c1 = __shfl(corr, 4 * g + 1);
      float c2 = __shfl(corr, 4 * g + 2);
      float c3 = __shfl(corr, 4 * g + 3);
#pragma unroll
      for (int nt = 0; nt < 4; nt++) {
        acc_o[nt][0] *= c0; acc_o[nt][1] *= c1;
        acc_o[nt][2] *= c2; acc_o[nt][3] *= c3;
      }
      l_run *= corr;
      m_run = m_new;
    }

    float p[4][4];
    float ps = 0.f;
#pragma unroll
    for (int mt = 0; mt < 4; mt++)
#pragma unroll
      for (int i = 0; i < 4; i++) {
        p[mt][i] = exp2f(s_[mt][i] - m_run);   // bounded by 2^8
        ps += p[mt][i];
      }
    ps += __shfl_xor(ps, 16);
    ps += __shfl_xor(ps, 32);
    l_run += ps;

    // write P (bf16, cheap pack) to wave-private LDS: row q=li, keys 16mt+4g+i
#pragma unroll
    for (int mt = 0; mt < 4; mt++) {
      uint2 pv;
      pv.x = pack_bf(p[mt][0], p[mt][1]);
      pv.y = pack_bf(p[mt][2], p[mt][3]);
      *(uint2*)((char*)&Ps[wv][0] + li * 128 +
                (((2 * mt + (g >> 1)) ^ (li & 7)) << 4) + ((g & 1) << 3)) = pv;
    }

    // O += P . V   (A = P rows q, B = V^T rows d from Vs)
#pragma unroll
    for (int s = 0; s < 2; s++) {
      bf16x8 pa = ((const bf16x8*)&Ps[wv][0])[li * 8 + ((g + 4 * s) ^ (li & 7))];
#pragma unroll
      for (int nt = 0; nt < 4; nt++) {
        int row = 16 * nt + li;
        bf16x8 vb = ((const bf16x8*)Vs)[row * 8 + ((g + 4 * s) ^ (row & 7))];
        acc_o[nt] = __builtin_amdgcn_mfma_f32_16x16x32_bf16(pa, vb, acc_o[nt], 0, 0, 0);
      }
    }
  }

  float linv[4];
#pragma unroll
  for (int i = 0; i < 4; i++) linv[i] = 1.f / __shfl(l_run, 4 * g + i);
#pragma unroll
  for (int i = 0; i < 4; i++) {
    size_t roff = (tb + q0 + wv * 16 + 4 * g + i) * 512 + h * 64;
#pragma unroll
    for (int nt = 0; nt < 4; nt++)
      ctx[roff + 16 * nt + li] = f2bf(acc_o[nt][i] * linv[i]);
  }
}

// ---------------- LayerNorm over E=512; one wave per row; f32 + bf16 out ------
__global__ __launch_bounds__(256) void ln_kernel(
    const float* __restrict__ X, const float* __restrict__ g,
    const float* __restrict__ b, float* __restrict__ Yf,
    unsigned short* __restrict__ Yb)
{
  int t = threadIdx.x, lane = t & 63, wv = t >> 6;
  size_t row = (size_t)blockIdx.x * 4 + wv;
  const float* xp = X + row * 512 + lane * 8;
  float4 a = *(const float4*)xp;
  float4 c = *(const float4*)(xp + 4);
  float sum = a.x + a.y + a.z + a.w + c.x + c.y + c.z + c.w;
  float sq  = a.x*a.x + a.y*a.y + a.z*a.z + a.w*a.w
            + c.x*c.x + c.y*c.y + c.z*c.z + c.w*c.w;
#pragma unroll
  for (int off = 32; off > 0; off >>= 1) {
    sum += __shfl_xor(sum, off);
    sq  += __shfl_xor(sq, off);
  }
  float mu  = sum * (1.0f / 512.0f);
  float inv = rsqrtf(sq * (1.0f / 512.0f) - mu * mu + 1e-5f);
  float4 g0 = *(const float4*)(g + lane * 8);
  float4 g1 = *(const float4*)(g + lane * 8 + 4);
  float4 b0 = *(const float4*)(b + lane * 8);
  float4 b1 = *(const float4*)(b + lane * 8 + 4);
  float y[8];
  y[0] = (a.x - mu) * inv * g0.x + b0.x;
  y[1] = (a.y - mu) * inv * g0.y + b0.y;
  y[2] = (a.z - mu) * inv * g0.z + b0.z;
  y[3] = (a.w - mu) * inv * g0.w + b0.w;
  y[4] = (c.x - mu) * inv * g1.x + b1.x;
  y[5] = (c.y - mu) * inv * g1.y + b1.y;
  y[6] = (c.z - mu) * inv * g1.z + b1.z;
  y[7] = (c.w - mu) * inv * g1.w + b1.w;
  float4 y0 = {y[0], y[1], y[2], y[3]};
  float4 y1 = {y[4], y[5], y[6], y[7]};
  *(float4*)(Yf + row * 512 + lane * 8)     = y0;
  *(float4*)(Yf + row * 512 + lane * 8 + 4) = y1;
  bf16x8 yb;
#pragma unroll
  for (int j = 0; j < 8; j++) yb[j] = (short)f2bf(y[j]);
  *(bf16x8*)(Yb + row * 512 + lane * 8) = yb;
}

// ---------------- final projection: [8192,512] @ [32,512]^T + b ----------------
__global__ __launch_bounds__(256) void outp_kernel(
    const float* __restrict__ X, const float* __restrict__ W,
    const float* __restrict__ bias, float* __restrict__ Y)
{
  __shared__ __align__(16) float Xs[8][516];
  int t = threadIdx.x;
  int r = t >> 5, n = t & 31;
  size_t rowbase = (size_t)blockIdx.x * 8;
  const float* xp = X + (rowbase + r) * 512 + n * 16;
#pragma unroll
  for (int j = 0; j < 4; j++) {
    float4 v = *(const float4*)(xp + j * 4);
    *(float4*)&Xs[r][n * 16 + j * 4] = v;
  }
  __syncthreads();
  float acc = bias[n];
  const float* wp = W + (size_t)n * 512;
#pragma unroll 4
  for (int k0 = 0; k0 < 512; k0 += 4) {
    float4 h4 = *(const float4*)&Xs[r][k0];
    float4 w4 = *(const float4*)(wp + k0);
    acc += h4.x * w4.x + h4.y * w4.y + h4.z * w4.z + h4.w * w4.w;
  }
  Y[(rowbase + r) * 32 + n] = acc;
}

extern "C" void kernel_launch(void* const* d_in, const int* in_sizes, int n_in,
                              void* d_out, int out_size, void* d_ws, size_t ws_size,
                              hipStream_t stream) {
  (void)in_sizes; (void)n_in; (void)out_size; (void)ws_size;
  const float* x      = (const float*)d_in[0];
  const float* conv_w = (const float*)d_in[1];
  const float* conv_b = (const float*)d_in[2];
  const float* qkv_w  = (const float*)d_in[3];
  const float* qkv_b  = (const float*)d_in[4];
  const float* out_w  = (const float*)d_in[5];
  const float* out_b  = (const float*)d_in[6];
  const float* fc1_w  = (const float*)d_in[7];
  const float* fc1_b  = (const float*)d_in[8];
  const float* fc2_w  = (const float*)d_in[9];
  const float* fc2_b  = (const float*)d_in[10];
  const float* ln1_w  = (const float*)d_in[11];
  const float* ln1_b  = (const float*)d_in[12];
  const float* ln2_w  = (const float*)d_in[13];
  const float* ln2_b  = (const float*)d_in[14];
  const float* outp_w = (const float*)d_in[15];
  const float* outp_b = (const float*)d_in[16];
  float* out = (float*)d_out;

  char* p = (char*)d_ws;
  unsigned short* A_bf = (unsigned short*)p;            p += (size_t)8192 * 512 * 2;
  float*          A_f  = (float*)p;                     p += (size_t)8192 * 512 * 4;
  unsigned short* QKV  = (unsigned short*)p;            p += (size_t)8192 * 1536 * 2;
  unsigned short* VT   = (unsigned short*)p;            p += (size_t)32 * 64 * 2048 * 2;
  unsigned short* CTX  = (unsigned short*)p;            p += (size_t)8192 * 512 * 2;
  unsigned short* Wq   = (unsigned short*)p;            p += (size_t)4 * 1536 * 512 * 2;
  unsigned short* Wo   = (unsigned short*)p;            p += (size_t)4 * 512 * 512 * 2;
  unsigned short* W1   = (unsigned short*)p;            p += (size_t)4 * 512 * 512 * 2;
  unsigned short* W2   = (unsigned short*)p;            p += (size_t)4 * 512 * 512 * 2;
  float* D = (float*)QKV;   // aliased: D[8192,512] f32 lives in QKV region (disjoint lifetime)

  f2bf_kernel<<<3072, 256, 0, stream>>>(qkv_w, Wq, 786432);
  f2bf_kernel<<<1024, 256, 0, stream>>>(out_w, Wo, 262144);
  f2bf_kernel<<<1024, 256, 0, stream>>>(fc1_w, W1, 262144);
  f2bf_kernel<<<1024, 256, 0, stream>>>(fc2_w, W2, 262144);

  conv_pe_kernel<<<1024, 256, 0, stream>>>(x, conv_w, conv_b, A_f, A_bf);

  for (int l = 0; l < 4; l++) {
    gemm_bf<0, 1><<<64 * 12, 256, 0, stream>>>(
        A_bf, Wq + (size_t)l * 1536 * 512, qkv_b + l * 1536, nullptr,
        QKV, nullptr, 1536);
    vtrans_kernel<<<1024, 256, 0, stream>>>(QKV, VT);
    attn_mfma<<<1024, 256, 0, stream>>>(QKV, VT, CTX);
    gemm_bf<1, 0><<<64 * 4, 256, 0, stream>>>(
        CTX, Wo + (size_t)l * 512 * 512, out_b + l * 512, A_f,
        nullptr, D, 512);
    ln_kernel<<<2048, 256, 0, stream>>>(D, ln1_w + l * 512, ln1_b + l * 512, A_f, A_bf);
    gemm_bf<2, 0><<<64 * 4, 256, 0, stream>>>(
        A_bf, W1 + (size_t)l * 512 * 512, fc1_b + l * 512, nullptr,
        CTX, nullptr, 512);
    gemm_bf<1, 0><<<64 * 4, 256, 0, stream>>>(
        CTX, W2 + (size_t)l * 512 * 512, fc2_b + l * 512, A_f,
        nullptr, D, 512);
    ln_kernel<<<2048, 256, 0, stream>>>(D, ln2_w + l * 512, ln2_b + l * 512, A_f, A_bf);
  }
  outp_kernel<<<1024, 256, 0, stream>>>(A_f, outp_w, outp_b, out);
}

// Round 5
// 736.664 us; speedup vs baseline: 1.1041x; 1.1041x over previous
//
#include <hip/hip_runtime.h>
#include <hip/hip_bf16.h>
#include <cstddef>

typedef short bf16x8 __attribute__((ext_vector_type(8)));
typedef float f32x4 __attribute__((ext_vector_type(4)));

__device__ __forceinline__ unsigned short f2bf(float x) {
  __hip_bfloat16 h = __float2bfloat16(x);
  unsigned short u; __builtin_memcpy(&u, &h, 2); return u;
}

// async global->LDS, 16B per lane; lds dest = wave-uniform base + lane*16
__device__ __forceinline__ void gload16(const unsigned short* g, unsigned short* l) {
  __builtin_amdgcn_global_load_lds(
      (const __attribute__((address_space(1))) void*)g,
      (__attribute__((address_space(3))) void*)l, 16, 0, 0);
}

// ---------------- weight fp32 -> bf16 convert ----------------
__global__ __launch_bounds__(256) void f2bf_kernel(
    const float* __restrict__ src, unsigned short* __restrict__ dst, int n4)
{
  int i = blockIdx.x * 256 + threadIdx.x;
  if (i < n4) {
    float4 v = *(const float4*)(src + (size_t)i * 4);
    ushort4 o;
    o.x = f2bf(v.x); o.y = f2bf(v.y); o.z = f2bf(v.z); o.w = f2bf(v.w);
    *(ushort4*)(dst + (size_t)i * 4) = o;
  }
}

// ---------------- conv1d (circular, k=3) + positional embedding ----------------
__global__ __launch_bounds__(256) void conv_pe_kernel(
    const float* __restrict__ x, const float* __restrict__ cw,
    const float* __restrict__ cb,
    float* __restrict__ outf, unsigned short* __restrict__ outb)
{
  const int L = 2048, CIN = 32;
  int b  = blockIdx.x >> 8;
  int l0 = (blockIdx.x & 255) << 3;
  int t  = threadIdx.x;
  __shared__ float xs[10][32];
  for (int idx = t; idx < 320; idx += 256) {
    int rr = idx >> 5, ci = idx & 31;
    int gl = (l0 - 1 + rr + L) & (L - 1);
    xs[rr][ci] = x[((size_t)b * L + gl) * CIN + ci];
  }
  __syncthreads();
  int e0 = t << 1;
  float acc0[8], acc1[8];
  float bb0 = cb[e0], bb1 = cb[e0 + 1];
#pragma unroll
  for (int li = 0; li < 8; li++) { acc0[li] = bb0; acc1[li] = bb1; }
  const float* w0p = cw + (size_t)e0 * 96;
  const float* w1p = w0p + 96;
  for (int ci = 0; ci < 32; ci++) {
#pragma unroll
    for (int kk = 0; kk < 3; kk++) {
      float w0 = w0p[ci * 3 + kk];
      float w1 = w1p[ci * 3 + kk];
#pragma unroll
      for (int li = 0; li < 8; li++) {
        float xv = xs[li + kk][ci];
        acc0[li] += xv * w0;
        acc1[li] += xv * w1;
      }
    }
  }
  float dv = __expf((float)e0 * (-9.210340371976184f / 512.0f));
#pragma unroll
  for (int li = 0; li < 8; li++) {
    int l = l0 + li;
    float arg = (float)l * dv;
    float sv = sinf(arg), cv = cosf(arg);
    float2 o; o.x = acc0[li] + sv; o.y = acc1[li] + cv;
    size_t off = ((size_t)b * L + l) * 512 + e0;
    *(float2*)&outf[off] = o;
    ushort2 ob; ob.x = f2bf(o.x); ob.y = f2bf(o.y);
    *(ushort2*)&outb[off] = ob;
  }
}

// ---------------- bf16 MFMA GEMM: Y[M,N] = X[M,512] @ W[N,512]^T + bias ----------
// EPI 0: Y bf16.  EPI 1: Y f32 = acc + bias + R(f32).  EPI 2: SiLU -> Y bf16.
// QSCALE: multiply cols [0,512) by softmax prescale (for fused Q scaling).
// Staging: global_load_lds w=16, linear LDS dest, inverse-swizzled global source.
template<int EPI, int QSCALE>
__global__ __launch_bounds__(256) void gemm_bf(
    const unsigned short* __restrict__ X,
    const unsigned short* __restrict__ W,
    const float* __restrict__ bias,
    const float* __restrict__ R,
    unsigned short* __restrict__ Yb,
    float* __restrict__ Yf,
    int N)
{
  const int K = 512;
  __shared__ unsigned short Xs[128 * 64];
  __shared__ unsigned short Ws[128 * 64];
  int t = threadIdx.x;
  int lane = t & 63, wv = t >> 6;
  int g = lane >> 4, li = lane & 15;
  int m0 = (blockIdx.x & 63) << 7;
  int n0 = (blockIdx.x >> 6) << 7;
  int wm = (wv >> 1) << 6, wn = (wv & 1) << 6;

  // staging geometry: slot idx = (wv*4+j)*64 + lane; row = idx>>3, sl = lane&7
  int subrow = lane >> 3;                       // row&7 for every issue
  int coloff = ((lane & 7) ^ subrow) << 3;      // shorts; inverse swizzle on source

  f32x4 acc[4][4];
#pragma unroll
  for (int a = 0; a < 4; a++)
#pragma unroll
    for (int b2 = 0; b2 < 4; b2++) acc[a][b2] = (f32x4){0.f, 0.f, 0.f, 0.f};

  for (int k0 = 0; k0 < K; k0 += 64) {
    __syncthreads();                 // all waves done reading previous tile
#pragma unroll
    for (int j = 0; j < 4; j++) {
      int row = (wv * 4 + j) * 8 + subrow;
      gload16(X + (size_t)(m0 + row) * K + k0 + coloff, Xs + (wv * 4 + j) * 512);
      gload16(W + (size_t)(n0 + row) * K + k0 + coloff, Ws + (wv * 4 + j) * 512);
    }
    __syncthreads();                 // implicit vmcnt(0) drain -> data visible
#pragma unroll
    for (int s = 0; s < 2; s++) {
      bf16x8 af[4], bfr[4];
#pragma unroll
      for (int mt = 0; mt < 4; mt++) {
        int row = wm + 16 * mt + li;
        af[mt] = ((const bf16x8*)Xs)[row * 8 + ((g + 4 * s) ^ (row & 7))];
      }
#pragma unroll
      for (int nt = 0; nt < 4; nt++) {
        int row = wn + 16 * nt + li;
        bfr[nt] = ((const bf16x8*)Ws)[row * 8 + ((g + 4 * s) ^ (row & 7))];
      }
#pragma unroll
      for (int mt = 0; mt < 4; mt++)
#pragma unroll
        for (int nt = 0; nt < 4; nt++)
          acc[mt][nt] = __builtin_amdgcn_mfma_f32_16x16x32_bf16(
              af[mt], bfr[nt], acc[mt][nt], 0, 0, 0);
    }
  }
  float bv[4];
#pragma unroll
  for (int nt = 0; nt < 4; nt++) bv[nt] = bias[n0 + wn + 16 * nt + li];
#pragma unroll
  for (int mt = 0; mt < 4; mt++) {
#pragma unroll
    for (int i = 0; i < 4; i++) {
      size_t roff = (size_t)(m0 + wm + 16 * mt + 4 * g + i) * N;
#pragma unroll
      for (int nt = 0; nt < 4; nt++) {
        int col = n0 + wn + 16 * nt + li;
        float v = acc[mt][nt][i] + bv[nt];
        if (EPI == 1) {
          v += R[roff + col];
          Yf[roff + col] = v;
        } else if (EPI == 2) {
          v = v / (1.f + __expf(-v));
          Yb[roff + col] = f2bf(v);
        } else {
          if (QSCALE && col < 512) v *= 0.18033688011112042f;  // 0.125*log2(e)
          Yb[roff + col] = f2bf(v);
        }
      }
    }
  }
}

// ---------------- V transpose: qkv_bf V-part -> Vt[32][64][2048] ----------------
__global__ __launch_bounds__(256) void vtrans_kernel(
    const unsigned short* __restrict__ qkv, unsigned short* __restrict__ Vt)
{
  int ki = blockIdx.x & 31, bh = blockIdx.x >> 5;
  int b = bh >> 3, h = bh & 7;
  int kt = ki << 6;
  __shared__ unsigned short T[64][72];
  int t = threadIdx.x;
  int r = t >> 2, c0 = (t & 3) << 4;
  const unsigned short* src =
      qkv + ((size_t)(b * 2048 + kt + r)) * 1536 + 1024 + h * 64 + c0;
  bf16x8 a0 = *(const bf16x8*)src;
  bf16x8 a1 = *(const bf16x8*)(src + 8);
  *(bf16x8*)&T[r][c0] = a0;
  *(bf16x8*)&T[r][c0 + 8] = a1;
  __syncthreads();
  int d = t >> 2, k0 = (t & 3) << 4;
  bf16x8 v0, v1;
#pragma unroll
  for (int j = 0; j < 8; j++) v0[j] = (short)T[k0 + j][d];
#pragma unroll
  for (int j = 0; j < 8; j++) v1[j] = (short)T[k0 + 8 + j][d];
  unsigned short* dst = Vt + ((size_t)bh * 64 + d) * 2048 + kt + k0;
  *(bf16x8*)dst = v0;
  *(bf16x8*)(dst + 8) = v1;
}

// ---------------- MFMA flash attention: H=8, HD=64, L=2048 ----------------
// grid: 32 q-tiles x 32 bh; 256 thr = 4 waves, 16 q-rows/wave, 64-key tiles
// Q comes PRE-SCALED by 0.125*log2(e): scores are exp2-domain.
__global__ __launch_bounds__(256) void attn_mfma(
    const unsigned short* __restrict__ qkv,  // [8192,1536] bf16 (Q prescaled)
    const unsigned short* __restrict__ Vt,   // [32,64,2048] bf16
    unsigned short* __restrict__ ctx)        // [8192,512] bf16
{
  const int L = 2048;
  int qi = blockIdx.x & 31, bh = blockIdx.x >> 5;
  int b = bh >> 3, h = bh & 7;
  int q0 = qi << 6;
  size_t tb = (size_t)b * L;
  int t = threadIdx.x, lane = t & 63, wv = t >> 6;
  int g = lane >> 4, li = lane & 15;

  __shared__ unsigned short Ks[64 * 64];   // [key][d], slot^=(key&7)
  __shared__ unsigned short Vs[64 * 64];   // [d][key], slot^=(d&7)
  __shared__ unsigned short Ps[4][16 * 64];// per-wave [q][key], slot^=(q&7)

  bf16x8 qf[2];
  {
    const unsigned short* qp =
        qkv + (tb + q0 + wv * 16 + li) * 1536 + h * 64 + g * 8;
    qf[0] = *(const bf16x8*)qp;
    qf[1] = *(const bf16x8*)(qp + 32);
  }

  f32x4 acc_o[4];
#pragma unroll
  for (int nt = 0; nt < 4; nt++) acc_o[nt] = (f32x4){0.f, 0.f, 0.f, 0.f};
  float m_run = -1e30f, l_run = 0.f;

  // staging geometry (gload16): slot idx = (wv*2+j)*64 + lane
  int subrow = lane >> 3;
  int coloff = ((lane & 7) ^ subrow) << 3;        // shorts
  const unsigned short* Kb = qkv + tb * 1536 + 512 + h * 64;
  const unsigned short* Vb = Vt + (size_t)bh * 64 * 2048;

  for (int kt = 0; kt < L; kt += 64) {
    __syncthreads();                 // all waves done with previous tile
#pragma unroll
    for (int j = 0; j < 2; j++) {
      int row = (wv * 2 + j) * 8 + subrow;
      gload16(Kb + (size_t)(kt + row) * 1536 + coloff, Ks + (wv * 2 + j) * 512);
      gload16(Vb + (size_t)row * 2048 + kt + coloff, Vs + (wv * 2 + j) * 512);
    }
    __syncthreads();                 // vmcnt drain -> tile visible

    // S^T[key][q] = K . Q^T  (A = K rows, B = Q)
    f32x4 s_[4];
#pragma unroll
    for (int mt = 0; mt < 4; mt++) s_[mt] = (f32x4){0.f, 0.f, 0.f, 0.f};
#pragma unroll
    for (int s = 0; s < 2; s++) {
#pragma unroll
      for (int mt = 0; mt < 4; mt++) {
        int row = 16 * mt + li;
        bf16x8 kf = ((const bf16x8*)Ks)[row * 8 + ((g + 4 * s) ^ (row & 7))];
        s_[mt] = __builtin_amdgcn_mfma_f32_16x16x32_bf16(kf, qf[s], s_[mt], 0, 0, 0);
      }
    }

    // tile max for this lane's q-row (lane owns q=li)
    float mx = fmaxf(fmaxf(s_[0][0], s_[0][1]), fmaxf(s_[0][2], s_[0][3]));
#pragma unroll
    for (int mt = 1; mt < 4; mt++)
      mx = fmaxf(mx, fmaxf(fmaxf(s_[mt][0], s_[mt][1]), fmaxf(s_[mt][2], s_[mt][3])));
    mx = fmaxf(mx, __shfl_xor(mx, 16));
    mx = fmaxf(mx, __shfl_xor(mx, 32));

    // defer-max (T13): rescale only when some row's max grew past THR=8
    if (__any(mx > m_run + 8.0f)) {
      float m_new = fmaxf(m_run, mx);
      float corr = exp2f(m_run - m_new);          // cold path
      float c0 = __shfl(corr, 4 * g + 0);
      float c1 = __shfl(corr, 4 * g + 1);
      float c2 = __shfl(corr, 4 * g + 2);
      float c3 = __shfl(corr, 4 * g + 3);
#pragma unroll
      for (int nt = 0; nt < 4; nt++) {
        acc_o[nt][0] *= c0; acc_o[nt][1] *= c1;
        acc_o[nt][2] *= c2; acc_o[nt][3] *= c3;
      }
      l_run *= corr;
      m_run = m_new;
    }

    // p = 2^(s - m_run): raw v_exp_f32 (batched, TRANS-hazard nop)
    float p[4][4];
#pragma unroll
    for (int mt = 0; mt < 4; mt++) {
#pragma unroll
      for (int i = 0; i < 4; i++) p[mt][i] = s_[mt][i] - m_run;
      asm volatile(
          "v_exp_f32 %0, %0\n\tv_exp_f32 %1, %1\n\t"
          "v_exp_f32 %2, %2\n\tv_exp_f32 %3, %3\n\ts_nop 1"
          : "+v"(p[mt][0]), "+v"(p[mt][1]), "+v"(p[mt][2]), "+v"(p[mt][3]));
    }
    float ps = 0.f;
#pragma unroll
    for (int mt = 0; mt < 4; mt++)
#pragma unroll
      for (int i = 0; i < 4; i++) ps += p[mt][i];
    ps += __shfl_xor(ps, 16);
    ps += __shfl_xor(ps, 32);
    l_run += ps;

    // write P (bf16 via v_cvt_pk) to wave-private LDS: row q=li
#pragma unroll
    for (int mt = 0; mt < 4; mt++) {
      uint2 pv;
      asm("v_cvt_pk_bf16_f32 %0, %1, %2" : "=v"(pv.x) : "v"(p[mt][0]), "v"(p[mt][1]));
      asm("v_cvt_pk_bf16_f32 %0, %1, %2" : "=v"(pv.y) : "v"(p[mt][2]), "v"(p[mt][3]));
      *(uint2*)((char*)&Ps[wv][0] + li * 128 +
                (((2 * mt + (g >> 1)) ^ (li & 7)) << 4) + ((g & 1) << 3)) = pv;
    }

    // O += P . V   (A = P rows q, B = V^T rows d from Vs)
#pragma unroll
    for (int s = 0; s < 2; s++) {
      bf16x8 pa = ((const bf16x8*)&Ps[wv][0])[li * 8 + ((g + 4 * s) ^ (li & 7))];
#pragma unroll
      for (int nt = 0; nt < 4; nt++) {
        int row = 16 * nt + li;
        bf16x8 vb = ((const bf16x8*)Vs)[row * 8 + ((g + 4 * s) ^ (row & 7))];
        acc_o[nt] = __builtin_amdgcn_mfma_f32_16x16x32_bf16(pa, vb, acc_o[nt], 0, 0, 0);
      }
    }
  }

  float linv[4];
#pragma unroll
  for (int i = 0; i < 4; i++) linv[i] = 1.f / __shfl(l_run, 4 * g + i);
#pragma unroll
  for (int i = 0; i < 4; i++) {
    size_t roff = (tb + q0 + wv * 16 + 4 * g + i) * 512 + h * 64;
#pragma unroll
    for (int nt = 0; nt < 4; nt++)
      ctx[roff + 16 * nt + li] = f2bf(acc_o[nt][i] * linv[i]);
  }
}

// ---------------- LayerNorm over E=512; one wave per row; f32 + bf16 out ------
__global__ __launch_bounds__(256) void ln_kernel(
    const float* __restrict__ X, const float* __restrict__ g,
    const float* __restrict__ b, float* __restrict__ Yf,
    unsigned short* __restrict__ Yb)
{
  int t = threadIdx.x, lane = t & 63, wv = t >> 6;
  size_t row = (size_t)blockIdx.x * 4 + wv;
  const float* xp = X + row * 512 + lane * 8;
  float4 a = *(const float4*)xp;
  float4 c = *(const float4*)(xp + 4);
  float sum = a.x + a.y + a.z + a.w + c.x + c.y + c.z + c.w;
  float sq  = a.x*a.x + a.y*a.y + a.z*a.z + a.w*a.w
            + c.x*c.x + c.y*c.y + c.z*c.z + c.w*c.w;
#pragma unroll
  for (int off = 32; off > 0; off >>= 1) {
    sum += __shfl_xor(sum, off);
    sq  += __shfl_xor(sq, off);
  }
  float mu  = sum * (1.0f / 512.0f);
  float inv = rsqrtf(sq * (1.0f / 512.0f) - mu * mu + 1e-5f);
  float4 g0 = *(const float4*)(g + lane * 8);
  float4 g1 = *(const float4*)(g + lane * 8 + 4);
  float4 b0 = *(const float4*)(b + lane * 8);
  float4 b1 = *(const float4*)(b + lane * 8 + 4);
  float y[8];
  y[0] = (a.x - mu) * inv * g0.x + b0.x;
  y[1] = (a.y - mu) * inv * g0.y + b0.y;
  y[2] = (a.z - mu) * inv * g0.z + b0.z;
  y[3] = (a.w - mu) * inv * g0.w + b0.w;
  y[4] = (c.x - mu) * inv * g1.x + b1.x;
  y[5] = (c.y - mu) * inv * g1.y + b1.y;
  y[6] = (c.z - mu) * inv * g1.z + b1.z;
  y[7] = (c.w - mu) * inv * g1.w + b1.w;
  float4 y0 = {y[0], y[1], y[2], y[3]};
  float4 y1 = {y[4], y[5], y[6], y[7]};
  *(float4*)(Yf + row * 512 + lane * 8)     = y0;
  *(float4*)(Yf + row * 512 + lane * 8 + 4) = y1;
  bf16x8 yb;
#pragma unroll
  for (int j = 0; j < 8; j++) yb[j] = (short)f2bf(y[j]);
  *(bf16x8*)(Yb + row * 512 + lane * 8) = yb;
}

// ---------------- final projection: [8192,512] @ [32,512]^T + b ----------------
__global__ __launch_bounds__(256) void outp_kernel(
    const float* __restrict__ X, const float* __restrict__ W,
    const float* __restrict__ bias, float* __restrict__ Y)
{
  __shared__ __align__(16) float Xs[8][516];
  int t = threadIdx.x;
  int r = t >> 5, n = t & 31;
  size_t rowbase = (size_t)blockIdx.x * 8;
  const float* xp = X + (rowbase + r) * 512 + n * 16;
#pragma unroll
  for (int j = 0; j < 4; j++) {
    float4 v = *(const float4*)(xp + j * 4);
    *(float4*)&Xs[r][n * 16 + j * 4] = v;
  }
  __syncthreads();
  float acc = bias[n];
  const float* wp = W + (size_t)n * 512;
#pragma unroll 4
  for (int k0 = 0; k0 < 512; k0 += 4) {
    float4 h4 = *(const float4*)&Xs[r][k0];
    float4 w4 = *(const float4*)(wp + k0);
    acc += h4.x * w4.x + h4.y * w4.y + h4.z * w4.z + h4.w * w4.w;
  }
  Y[(rowbase + r) * 32 + n] = acc;
}

extern "C" void kernel_launch(void* const* d_in, const int* in_sizes, int n_in,
                              void* d_out, int out_size, void* d_ws, size_t ws_size,
                              hipStream_t stream) {
  (void)in_sizes; (void)n_in; (void)out_size; (void)ws_size;
  const float* x      = (const float*)d_in[0];
  const float* conv_w = (const float*)d_in[1];
  const float* conv_b = (const float*)d_in[2];
  const float* qkv_w  = (const float*)d_in[3];
  const float* qkv_b  = (const float*)d_in[4];
  const float* out_w  = (const float*)d_in[5];
  const float* out_b  = (const float*)d_in[6];
  const float* fc1_w  = (const float*)d_in[7];
  const float* fc1_b  = (const float*)d_in[8];
  const float* fc2_w  = (const float*)d_in[9];
  const float* fc2_b  = (const float*)d_in[10];
  const float* ln1_w  = (const float*)d_in[11];
  const float* ln1_b  = (const float*)d_in[12];
  const float* ln2_w  = (const float*)d_in[13];
  const float* ln2_b  = (const float*)d_in[14];
  const float* outp_w = (const float*)d_in[15];
  const float* outp_b = (const float*)d_in[16];
  float* out = (float*)d_out;

  char* p = (char*)d_ws;
  unsigned short* A_bf = (unsigned short*)p;            p += (size_t)8192 * 512 * 2;
  float*          A_f  = (float*)p;                     p += (size_t)8192 * 512 * 4;
  unsigned short* QKV  = (unsigned short*)p;            p += (size_t)8192 * 1536 * 2;
  unsigned short* VT   = (unsigned short*)p;            p += (size_t)32 * 64 * 2048 * 2;
  unsigned short* CTX  = (unsigned short*)p;            p += (size_t)8192 * 512 * 2;
  unsigned short* Wq   = (unsigned short*)p;            p += (size_t)4 * 1536 * 512 * 2;
  unsigned short* Wo   = (unsigned short*)p;            p += (size_t)4 * 512 * 512 * 2;
  unsigned short* W1   = (unsigned short*)p;            p += (size_t)4 * 512 * 512 * 2;
  unsigned short* W2   = (unsigned short*)p;            p += (size_t)4 * 512 * 512 * 2;
  float* D = (float*)QKV;   // aliased: D[8192,512] f32 lives in QKV region (disjoint lifetime)

  f2bf_kernel<<<3072, 256, 0, stream>>>(qkv_w, Wq, 786432);
  f2bf_kernel<<<1024, 256, 0, stream>>>(out_w, Wo, 262144);
  f2bf_kernel<<<1024, 256, 0, stream>>>(fc1_w, W1, 262144);
  f2bf_kernel<<<1024, 256, 0, stream>>>(fc2_w, W2, 262144);

  conv_pe_kernel<<<1024, 256, 0, stream>>>(x, conv_w, conv_b, A_f, A_bf);

  for (int l = 0; l < 4; l++) {
    gemm_bf<0, 1><<<64 * 12, 256, 0, stream>>>(
        A_bf, Wq + (size_t)l * 1536 * 512, qkv_b + l * 1536, nullptr,
        QKV, nullptr, 1536);
    vtrans_kernel<<<1024, 256, 0, stream>>>(QKV, VT);
    attn_mfma<<<1024, 256, 0, stream>>>(QKV, VT, CTX);
    gemm_bf<1, 0><<<64 * 4, 256, 0, stream>>>(
        CTX, Wo + (size_t)l * 512 * 512, out_b + l * 512, A_f,
        nullptr, D, 512);
    ln_kernel<<<2048, 256, 0, stream>>>(D, ln1_w + l * 512, ln1_b + l * 512, A_f, A_bf);
    gemm_bf<2, 0><<<64 * 4, 256, 0, stream>>>(
        A_bf, W1 + (size_t)l * 512 * 512, fc1_b + l * 512, nullptr,
        CTX, nullptr, 512);
    gemm_bf<1, 0><<<64 * 4, 256, 0, stream>>>(
        CTX, W2 + (size_t)l * 512 * 512, fc2_b + l * 512, A_f,
        nullptr, D, 512);
    ln_kernel<<<2048, 256, 0, stream>>>(D, ln2_w + l * 512, ln2_b + l * 512, A_f, A_bf);
  }
  outp_kernel<<<1024, 256, 0, stream>>>(A_f, outp_w, outp_b, out);
}